// Round 18
// baseline (293.607 us; speedup 1.0000x reference)
//
#include <hip/hip_runtime.h>

#define B_ 2
#define T_ 2048
#define C_ 1024
#define H_ 16
#define D_ 64
#define MLS (32 * 16 * 64)          // ml section size (floats)
#define PSZ ((size_t)32 * 16 * 64 * 64)  // partial-O section size (shorts)

using bf16x8 = __attribute__((ext_vector_type(8))) short;
using f32x4  = __attribute__((ext_vector_type(4))) float;

static __device__ __forceinline__ short f2bf(float f) {
  unsigned u = __builtin_bit_cast(unsigned, f);
  unsigned r = u + 0x7fffu + ((u >> 16) & 1u);
  return (short)(r >> 16);
}

#define GLD16(gp, lp) __builtin_amdgcn_global_load_lds( \
    (const __attribute__((address_space(1))) void*)(gp), \
    (__attribute__((address_space(3))) void*)(lp), 16, 0, 0)

// ---------------- fused prep: cast x; transpose-cast w_qkv, w_out; zero merge flags --------
__global__ __launch_bounds__(256) void prep(const float* __restrict__ x,
                                            const float* __restrict__ w_qkv,
                                            const float* __restrict__ w_out,
                                            short* __restrict__ xb,
                                            short* __restrict__ wqkvT,
                                            short* __restrict__ woutT,
                                            int* __restrict__ flags) {
  const int blk = blockIdx.x;
  if (blk >= 6144) {  // flag-zero block (512 flags)
    flags[threadIdx.x] = 0;
    flags[256 + threadIdx.x] = 0;
    return;
  }
  if (blk < 2048) {
    int base = blk * 2048 + threadIdx.x * 8;
    float4 a = *(const float4*)&x[base];
    float4 b = *(const float4*)&x[base + 4];
    short r[8];
    r[0] = f2bf(a.x); r[1] = f2bf(a.y); r[2] = f2bf(a.z); r[3] = f2bf(a.w);
    r[4] = f2bf(b.x); r[5] = f2bf(b.y); r[6] = f2bf(b.z); r[7] = f2bf(b.w);
    *(int4*)&xb[base] = *(int4*)r;
  } else {
    __shared__ float tile[32][33];
    const float* in; short* out; int R, N, tix, tiy;
    if (blk < 2048 + 3072) {
      int t = blk - 2048;
      in = w_qkv; out = wqkvT; R = 1024; N = 3072; tix = t % 96; tiy = t / 96;
    } else {
      int t = blk - 2048 - 3072;
      in = w_out; out = woutT; R = 1024; N = 1024; tix = t & 31; tiy = t >> 5;
    }
    const int bx = tix * 32, by = tiy * 32;
    const int tx = threadIdx.x & 31, ty = threadIdx.x >> 5;
    #pragma unroll
    for (int j = 0; j < 32; j += 8)
      tile[ty + j][tx] = in[(size_t)(by + ty + j) * N + bx + tx];
    __syncthreads();
    const int s = threadIdx.x;
    if (s < 128) {
      int row = s >> 2, seg = (s & 3) * 8;
      short r[8];
      #pragma unroll
      for (int j = 0; j < 8; ++j) r[j] = f2bf(tile[seg + j][row]);
      *(int4*)&out[(size_t)(bx + row) * R + by + seg] = *(int4*)r;
    }
  }
}

// ---------------- GEMM QKV: 128x128 tile, BK=64; coalesced epilogues via LDS ----------------
__global__ __launch_bounds__(256) void gemm_qkv(const short* __restrict__ A,
                                                const short* __restrict__ Bt,
                                                const float* __restrict__ bias,
                                                short* __restrict__ Qo,
                                                short* __restrict__ Ko,
                                                short* __restrict__ Vt) {
  __shared__ short smem[128 * 132];
  short* sA = smem;
  short* sB = smem + 128 * 64;
  const int tid = threadIdx.x;
  const int w = tid >> 6, lane = tid & 63;
  const int wm = w >> 1, wn = w & 1;
  const int g = lane >> 4, r16 = lane & 15;
  const int m0 = blockIdx.x * 128, n0 = blockIdx.y * 128;
  const int krow = lane >> 3, kslot = lane & 7;

  f32x4 acc[4][4] = {};

  for (int k0 = 0; k0 < 1024; k0 += 64) {
    __syncthreads();
    #pragma unroll
    for (int p = 0; p < 4; ++p) {
      int rbase = w * 32 + p * 8;
      int row = rbase + krow;
      GLD16(&A[(size_t)(m0 + row) * 1024 + k0 + ((kslot ^ (row & 7)) * 8)], &sA[rbase * 64]);
      GLD16(&Bt[(size_t)(n0 + row) * 1024 + k0 + ((kslot ^ (row & 7)) * 8)], &sB[rbase * 64]);
    }
    __syncthreads();
    bf16x8 af[4][2], bf[4][2];
    #pragma unroll
    for (int mi = 0; mi < 4; ++mi) {
      int row = wm * 64 + mi * 16 + r16;
      #pragma unroll
      for (int c = 0; c < 2; ++c)
        af[mi][c] = *(const bf16x8*)&sA[row * 64 + (((c * 4 + g) ^ (row & 7)) * 8)];
    }
    #pragma unroll
    for (int ni = 0; ni < 4; ++ni) {
      int row = wn * 64 + ni * 16 + r16;
      #pragma unroll
      for (int c = 0; c < 2; ++c)
        bf[ni][c] = *(const bf16x8*)&sB[row * 64 + (((c * 4 + g) ^ (row & 7)) * 8)];
    }
    __builtin_amdgcn_s_setprio(1);
    #pragma unroll
    for (int mi = 0; mi < 4; ++mi)
      #pragma unroll
      for (int ni = 0; ni < 4; ++ni) {
        acc[mi][ni] = __builtin_amdgcn_mfma_f32_16x16x32_bf16(af[mi][0], bf[ni][0], acc[mi][ni], 0, 0, 0);
        acc[mi][ni] = __builtin_amdgcn_mfma_f32_16x16x32_bf16(af[mi][1], bf[ni][1], acc[mi][ni], 0, 0, 0);
      }
    __builtin_amdgcn_s_setprio(0);
  }

  const int b2 = m0 >> 11, t0l = m0 & 2047;
  __syncthreads();

  if (n0 < 2048) {
    const int which = n0 >> 10;
    short* dst = (which == 0) ? Qo : Ko;
    const float sc = (which == 0) ? 0.18033688f : 1.0f;  // 0.125 * log2(e) into Q
    #pragma unroll
    for (int mi = 0; mi < 4; ++mi) {
      #pragma unroll
      for (int ni = 0; ni < 4; ++ni) {
        int nn = wn * 64 + ni * 16 + r16;
        float bv = bias[n0 + nn];
        #pragma unroll
        for (int rr = 0; rr < 4; ++rr) {
          int tm = wm * 64 + mi * 16 + g * 4 + rr;
          smem[tm * 132 + nn] = f2bf((acc[mi][ni][rr] + bv) * sc);
        }
      }
    }
    __syncthreads();
    const int h0 = (n0 & 1023) >> 6;
    const int c = lane & 15;
    const int head = h0 + (c >> 3);
    #pragma unroll
    for (int it = 0; it < 8; ++it) {
      int row = w * 32 + it * 4 + (lane >> 4);
      int4 v = *(const int4*)&smem[row * 132 + c * 8];
      *(int4*)&dst[(size_t)((b2 * H_ + head) * T_ + t0l + row) * 64 + (c & 7) * 8] = v;
    }
  } else {
    #pragma unroll
    for (int mi = 0; mi < 4; ++mi) {
      #pragma unroll
      for (int ni = 0; ni < 4; ++ni) {
        int nn = wn * 64 + ni * 16 + r16;
        float bv = bias[n0 + nn];
        #pragma unroll
        for (int rr = 0; rr < 4; ++rr) {
          int tm = wm * 64 + mi * 16 + g * 4 + rr;
          int tp = (tm & ~0x1C) | ((tm & 0xC) << 1) | ((tm & 0x10) >> 2);  // within-64 slot perm
          smem[nn * 132 + tp] = f2bf(acc[mi][ni][rr] + bv);
        }
      }
    }
    __syncthreads();
    const int head0 = b2 * H_ + ((n0 - 2048) >> 6);
    const int c = lane & 15;
    #pragma unroll
    for (int it = 0; it < 8; ++it) {
      int row = w * 32 + it * 4 + (lane >> 4);
      int d = row & 63, hh2 = row >> 6;
      int4 v = *(const int4*)&smem[row * 132 + c * 8];
      *(int4*)&Vt[((size_t)(head0 + hh2) * D_ + d) * T_ + t0l + c * 8] = v;
    }
  }
}

// ---------------- GEMM out: 128x64 tile (512 blocks = 2/CU), BK=64 ----------------
__global__ __launch_bounds__(256) void gemm_out(const short* __restrict__ A,
                                                const short* __restrict__ Bt,
                                                const float* __restrict__ bias,
                                                float* __restrict__ Out) {
  __shared__ short sA[128 * 64];
  __shared__ short sB[64 * 64];
  const int tid = threadIdx.x;
  const int w = tid >> 6, lane = tid & 63;
  const int wm = w >> 1, wn = w & 1;
  const int g = lane >> 4, r16 = lane & 15;
  const int m0 = blockIdx.x * 128, n0 = blockIdx.y * 64;
  const int krow = lane >> 3, kslot = lane & 7;

  f32x4 acc[4][2] = {};

  for (int k0 = 0; k0 < 1024; k0 += 64) {
    __syncthreads();
    #pragma unroll
    for (int p = 0; p < 4; ++p) {
      int rbase = w * 32 + p * 8;
      int row = rbase + krow;
      GLD16(&A[(size_t)(m0 + row) * 1024 + k0 + ((kslot ^ (row & 7)) * 8)], &sA[rbase * 64]);
    }
    #pragma unroll
    for (int p = 0; p < 2; ++p) {
      int rbase = w * 16 + p * 8;
      int row = rbase + krow;
      GLD16(&Bt[(size_t)(n0 + row) * 1024 + k0 + ((kslot ^ (row & 7)) * 8)], &sB[rbase * 64]);
    }
    __syncthreads();
    bf16x8 af[4][2], bf[2][2];
    #pragma unroll
    for (int mi = 0; mi < 4; ++mi) {
      int row = wm * 64 + mi * 16 + r16;
      #pragma unroll
      for (int c = 0; c < 2; ++c)
        af[mi][c] = *(const bf16x8*)&sA[row * 64 + (((c * 4 + g) ^ (row & 7)) * 8)];
    }
    #pragma unroll
    for (int ni = 0; ni < 2; ++ni) {
      int row = wn * 32 + ni * 16 + r16;
      #pragma unroll
      for (int c = 0; c < 2; ++c)
        bf[ni][c] = *(const bf16x8*)&sB[row * 64 + (((c * 4 + g) ^ (row & 7)) * 8)];
    }
    __builtin_amdgcn_s_setprio(1);
    #pragma unroll
    for (int mi = 0; mi < 4; ++mi)
      #pragma unroll
      for (int ni = 0; ni < 2; ++ni) {
        acc[mi][ni] = __builtin_amdgcn_mfma_f32_16x16x32_bf16(af[mi][0], bf[ni][0], acc[mi][ni], 0, 0, 0);
        acc[mi][ni] = __builtin_amdgcn_mfma_f32_16x16x32_bf16(af[mi][1], bf[ni][1], acc[mi][ni], 0, 0, 0);
      }
    __builtin_amdgcn_s_setprio(0);
  }

  #pragma unroll
  for (int mi = 0; mi < 4; ++mi) {
    #pragma unroll
    for (int ni = 0; ni < 2; ++ni) {
      int n = n0 + wn * 32 + ni * 16 + r16;
      float bv = bias[n];
      #pragma unroll
      for (int rr = 0; rr < 4; ++rr) {
        int m = m0 + wm * 64 + mi * 16 + g * 4 + rr;
        Out[(size_t)m * 1024 + n] = acc[mi][ni][rr] + bv;
      }
    }
  }
}

// ---------------- flash attention: K-split + all-DMA staging + fused last-block merge ------
// grid (bh=32, y=48); y -> (qi, split, half) as R15. Split halves write normalized partials
// to part[half] + (m,l) to ml, then last-finisher (atomic flag) merges and writes final O.
__global__ __launch_bounds__(256, 4) void attn_fwd(const short* __restrict__ Q,
                                                   const short* __restrict__ K,
                                                   const short* __restrict__ Vt,
                                                   short* __restrict__ O,
                                                   short* __restrict__ part,
                                                   float* __restrict__ ml,
                                                   int* __restrict__ flags) {
  __shared__ short sK[2][64 * 64];   // [key][d],  chunk c holds d-chunk c^(key&7)
  __shared__ short vT[2][64 * 64];   // [d][slot], chunk c holds slot-chunk c^(d&7)
  __shared__ int sflag;

  const int tid = threadIdx.x;
  const int w = tid >> 6, lane = tid & 63;
  const int g = lane >> 4, r16 = lane & 15;
  const int bh = blockIdx.x;
  const int b = bh >> 4, hh = bh & 15;
  const int yy = blockIdx.y;
  const int k3 = yy / 3, r3 = yy - 3 * k3;
  const int split = (r3 != 2);
  const int qi = split ? (31 - k3) : (15 - k3);
  const int half = split ? r3 : 0;
  const int q0 = qi * 64;
  const int kt0 = (split && half) ? ((qi + 1) >> 1) : 0;
  const int kt1 = (split && !half) ? ((qi + 1) >> 1) : (qi + 1);

  const short* Qh = Q + (size_t)bh * T_ * D_;
  const short* Kh = K + (size_t)bh * T_ * D_;
  const short* Vh = Vt + (size_t)bh * D_ * T_;   // [d][t'] slot-permuted

  const int krw = lane >> 3;
  const int kslot = lane & 7;

  const int qrow_a = q0 + w * 16 + r16;
  bf16x8 qf[2];
  qf[0] = *(const bf16x8*)&Qh[(size_t)qrow_a * 64 + g * 8];
  qf[1] = *(const bf16x8*)&Qh[(size_t)qrow_a * 64 + 32 + g * 8];

  f32x4 o[4] = {};
  float m_ = -1e30f, l_ = 0.f;   // per-lane partial l (scale 2^-m_)

  {
    const int k0 = kt0 * 64;
    #pragma unroll
    for (int p = 0; p < 2; ++p) {
      int row = w * 16 + p * 8 + krw;
      GLD16(&Kh[(size_t)(k0 + row) * 64 + ((kslot ^ (row & 7)) * 8)],
            &sK[0][(w * 16 + p * 8) * 64]);
      GLD16(&Vh[(size_t)row * T_ + k0 + ((kslot ^ (row & 7)) * 8)],
            &vT[0][(w * 16 + p * 8) * 64]);
    }
  }
  __syncthreads();

  for (int kt = kt0; kt < kt1; ++kt) {
    const int cur = (kt - kt0) & 1, nxt = cur ^ 1;
    const int k0 = kt * 64;
    const bool pf = (kt + 1 < kt1);

    if (pf) {
      const int k1 = k0 + 64;
      #pragma unroll
      for (int p = 0; p < 2; ++p) {
        int row = w * 16 + p * 8 + krw;
        GLD16(&Kh[(size_t)(k1 + row) * 64 + ((kslot ^ (row & 7)) * 8)],
              &sK[nxt][(w * 16 + p * 8) * 64]);
        GLD16(&Vh[(size_t)row * T_ + k1 + ((kslot ^ (row & 7)) * 8)],
              &vT[nxt][(w * 16 + p * 8) * 64]);
      }
    }

    // ---- S^T = K Q^T : lane holds S[key = nt*16+4g+rr][q = r16] ----
    f32x4 s[4] = {};
    __builtin_amdgcn_s_setprio(1);
    #pragma unroll
    for (int nt = 0; nt < 4; ++nt) {
      const int row = nt * 16 + r16;
      const int sw8 = r16 & 7;
      bf16x8 kf0 = *(const bf16x8*)&sK[cur][row * 64 + ((g ^ sw8) * 8)];
      bf16x8 kf1 = *(const bf16x8*)&sK[cur][row * 64 + (((4 + g) ^ sw8) * 8)];
      s[nt] = __builtin_amdgcn_mfma_f32_16x16x32_bf16(kf0, qf[0], s[nt], 0, 0, 0);
      s[nt] = __builtin_amdgcn_mfma_f32_16x16x32_bf16(kf1, qf[1], s[nt], 0, 0, 0);
    }
    __builtin_amdgcn_s_setprio(0);

    // ---- online softmax: zero cross-lane ops in the common path ----
    if (kt == qi) {
      const int qrow = w * 16 + r16;
      #pragma unroll
      for (int nt = 0; nt < 4; ++nt)
        #pragma unroll
        for (int rr = 0; rr < 4; ++rr)
          if (nt * 16 + 4 * g + rr > qrow) s[nt][rr] = -1e30f;
    }
    float pmax = s[0][0];
    #pragma unroll
    for (int nt = 0; nt < 4; ++nt)
      #pragma unroll
      for (int rr = 0; rr < 4; ++rr)
        pmax = fmaxf(pmax, s[nt][rr]);
    if (!__all(pmax - m_ <= 8.0f)) {  // defer-max (T13)
      float rmax = fmaxf(pmax, __shfl_xor(pmax, 16));
      rmax = fmaxf(rmax, __shfl_xor(rmax, 32));
      float mn = fmaxf(m_, rmax);
      float al = __builtin_amdgcn_exp2f(m_ - mn);
      m_ = mn;
      l_ *= al;
      float av[4];
      #pragma unroll
      for (int rr = 0; rr < 4; ++rr) av[rr] = __shfl(al, 4 * g + rr, 16);
      #pragma unroll
      for (int nt = 0; nt < 4; ++nt)
        #pragma unroll
        for (int rr = 0; rr < 4; ++rr) o[nt][rr] *= av[rr];
    }
    float rs = 0.f;
    #pragma unroll
    for (int nt = 0; nt < 4; ++nt)
      #pragma unroll
      for (int rr = 0; rr < 4; ++rr) {
        float p = __builtin_amdgcn_exp2f(s[nt][rr] - m_);
        s[nt][rr] = p;
        rs += p;
      }
    l_ += rs;
    int pk[8];
    #pragma unroll
    for (int nt = 0; nt < 4; ++nt)
      #pragma unroll
      for (int h = 0; h < 2; ++h)
        asm("v_cvt_pk_bf16_f32 %0, %1, %2"
            : "=v"(pk[nt * 2 + h])
            : "v"(s[nt][2 * h]), "v"(s[nt][2 * h + 1]));

    // ---- O += P @ V : packed P is the A-fragment directly ----
    bf16x8 pa[2];
    {
      int4 t0; t0.x = pk[0]; t0.y = pk[1]; t0.z = pk[2]; t0.w = pk[3];
      int4 t1; t1.x = pk[4]; t1.y = pk[5]; t1.z = pk[6]; t1.w = pk[7];
      pa[0] = __builtin_bit_cast(bf16x8, t0);
      pa[1] = __builtin_bit_cast(bf16x8, t1);
    }
    __builtin_amdgcn_s_setprio(1);
    #pragma unroll
    for (int nt = 0; nt < 4; ++nt) {
      const int d = nt * 16 + r16;
      bf16x8 vb0 = *(const bf16x8*)&vT[cur][d * 64 + ((g ^ (d & 7)) * 8)];
      bf16x8 vb1 = *(const bf16x8*)&vT[cur][d * 64 + (((4 + g) ^ (d & 7)) * 8)];
      o[nt] = __builtin_amdgcn_mfma_f32_16x16x32_bf16(pa[0], vb0, o[nt], 0, 0, 0);
      o[nt] = __builtin_amdgcn_mfma_f32_16x16x32_bf16(pa[1], vb1, o[nt], 0, 0, 0);
    }
    __builtin_amdgcn_s_setprio(0);

    __syncthreads();
  }

  // ---- epilogue: reduce per-lane l partials once ----
  float lt = l_ + __shfl_xor(l_, 16);
  lt += __shfl_xor(lt, 32);
  float lv[4];
  #pragma unroll
  for (int rr = 0; rr < 4; ++rr) lv[rr] = __shfl(lt, 4 * g + rr, 16);

  if (!split) {
    #pragma unroll
    for (int nt = 0; nt < 4; ++nt) {
      int d = nt * 16 + r16;
      #pragma unroll
      for (int rr = 0; rr < 4; ++rr) {
        int t = q0 + w * 16 + 4 * g + rr;
        O[(size_t)(b * T_ + t) * C_ + hh * 64 + d] = f2bf(o[nt][rr] / lv[rr]);
      }
    }
    return;
  }

  // ---- split: write my normalized partial + (m,l); last finisher merges ----
  const int p = qi - 16;
  const int base = (bh * 16 + p) * 64;
  short* myp = part + half * PSZ;
  #pragma unroll
  for (int nt = 0; nt < 4; ++nt) {
    int d = nt * 16 + r16;
    #pragma unroll
    for (int rr = 0; rr < 4; ++rr) {
      int row = w * 16 + 4 * g + rr;
      myp[((size_t)(base + row)) * 64 + d] = f2bf(o[nt][rr] / lv[rr]);
    }
  }
  if (lane < 16) {
    int mi = base + w * 16 + lane;
    ml[half * MLS + mi] = m_;          // per-row max (lane == row's r16, g==0 slice)
    ml[(2 + half) * MLS + mi] = lt;
  }
  __threadfence();
  __syncthreads();
  if (tid == 0) sflag = atomicAdd(&flags[bh * 16 + p], 1);
  __syncthreads();
  if (sflag == 0) return;  // winner: partial stored, loser will merge
  __threadfence();         // acquire: other half's stores now visible

  const int oh = 1 - half;
  const volatile float* mlv = (const volatile float*)ml;
  const volatile unsigned short* op2 =
      (const volatile unsigned short*)(part + oh * PSZ);

  float mmv[4], w1v[4], w2v[4];
  #pragma unroll
  for (int rr = 0; rr < 4; ++rr) {
    int row = w * 16 + 4 * g + rr;
    float m1 = __shfl(m_, 4 * g + rr, 16);   // my per-row m
    float l1 = lv[rr];                        // my per-row l
    float m2 = mlv[oh * MLS + base + row];
    float l2 = mlv[(2 + oh) * MLS + base + row];
    float ms = fmaxf(m1, m2);
    float w1 = l1 * __builtin_amdgcn_exp2f(m1 - ms);
    float w2 = l2 * __builtin_amdgcn_exp2f(m2 - ms);
    float inv = 1.0f / (w1 + w2);
    mmv[rr] = ms; w1v[rr] = w1 * inv; w2v[rr] = w2 * inv;
  }
  #pragma unroll
  for (int nt = 0; nt < 4; ++nt) {
    int d = nt * 16 + r16;
    #pragma unroll
    for (int rr = 0; rr < 4; ++rr) {
      int row = w * 16 + 4 * g + rr;
      float mine = o[nt][rr] / lv[rr];
      float other = __builtin_bit_cast(
          float, ((unsigned)op2[((size_t)(base + row)) * 64 + d]) << 16);
      int t = q0 + row;
      O[(size_t)(b * T_ + t) * C_ + hh * 64 + d] = f2bf(w1v[rr] * mine + w2v[rr] * other);
    }
  }
}

extern "C" void kernel_launch(void* const* d_in, const int* in_sizes, int n_in,
                              void* d_out, int out_size, void* d_ws, size_t ws_size,
                              hipStream_t stream) {
  const float* x     = (const float*)d_in[0];
  const float* w_qkv = (const float*)d_in[1];
  const float* b_qkv = (const float*)d_in[2];
  const float* w_out = (const float*)d_in[3];
  const float* b_out = (const float*)d_in[4];
  float* out = (float*)d_out;

  char* ws = (char*)d_ws;
  if (ws_size < (size_t)(52u << 20)) return;

  short* xb     = (short*)(ws);                        // 8 MiB  [4096][1024] bf16
  short* wqkvT  = (short*)(ws + ((size_t)8u << 20));   // 6 MiB  (dead after gemm_qkv)
  short* woutT  = (short*)(ws + ((size_t)14u << 20));  // 2 MiB
  short* Qb     = (short*)(ws + ((size_t)16u << 20));  // 8 MiB  [B][H][T][D] (prescaled)
  short* Kb     = (short*)(ws + ((size_t)24u << 20));  // 8 MiB  [B][H][T][D]
  short* Vtb    = (short*)(ws + ((size_t)32u << 20));  // 8 MiB  [B][H][D][T'] slot-permuted
  short* attn_o = xb;                                  // xb dead after gemm_qkv
  short* part   = (short*)(ws + ((size_t)40u << 20));  // 8 MiB  partial O (2 halves)
  float* ml     = (float*)(ws + ((size_t)48u << 20));  // 0.5 MiB m/l partials
  int*   flags  = (int*)(ws + ((size_t)49u << 20));    // 2 KiB merge flags

  prep<<<6145, 256, 0, stream>>>(x, w_qkv, w_out, xb, wqkvT, woutT, flags);
  gemm_qkv<<<dim3(32, 24), 256, 0, stream>>>(xb, wqkvT, b_qkv, Qb, Kb, Vtb);
  attn_fwd<<<dim3(32, 48), 256, 0, stream>>>(Qb, Kb, Vtb, attn_o, part, ml, flags);
  gemm_out<<<dim3(32, 16), 256, 0, stream>>>(attn_o, woutT, b_out, out);
}

// Round 19
// 107.741 us; speedup vs baseline: 2.7251x; 2.7251x over previous
//
#include <hip/hip_runtime.h>

#define B_ 2
#define T_ 2048
#define C_ 1024
#define H_ 16
#define D_ 64
#define MLS (32 * 16 * 64)   // ml section size (floats)

using bf16x8 = __attribute__((ext_vector_type(8))) short;
using f32x4  = __attribute__((ext_vector_type(4))) float;

static __device__ __forceinline__ short f2bf(float f) {
  unsigned u = __builtin_bit_cast(unsigned, f);
  unsigned r = u + 0x7fffu + ((u >> 16) & 1u);
  return (short)(r >> 16);
}

#define GLD16(gp, lp) __builtin_amdgcn_global_load_lds( \
    (const __attribute__((address_space(1))) void*)(gp), \
    (__attribute__((address_space(3))) void*)(lp), 16, 0, 0)

// ---------------- fused prep: cast x -> bf16; transpose-cast w_qkv, w_out ----------------
__global__ __launch_bounds__(256) void prep(const float* __restrict__ x,
                                            const float* __restrict__ w_qkv,
                                            const float* __restrict__ w_out,
                                            short* __restrict__ xb,
                                            short* __restrict__ wqkvT,
                                            short* __restrict__ woutT) {
  const int blk = blockIdx.x;
  if (blk < 2048) {
    int base = blk * 2048 + threadIdx.x * 8;
    float4 a = *(const float4*)&x[base];
    float4 b = *(const float4*)&x[base + 4];
    short r[8];
    r[0] = f2bf(a.x); r[1] = f2bf(a.y); r[2] = f2bf(a.z); r[3] = f2bf(a.w);
    r[4] = f2bf(b.x); r[5] = f2bf(b.y); r[6] = f2bf(b.z); r[7] = f2bf(b.w);
    *(int4*)&xb[base] = *(int4*)r;
  } else {
    __shared__ float tile[32][33];
    const float* in; short* out; int R, N, tix, tiy;
    if (blk < 2048 + 3072) {
      int t = blk - 2048;
      in = w_qkv; out = wqkvT; R = 1024; N = 3072; tix = t % 96; tiy = t / 96;
    } else {
      int t = blk - 2048 - 3072;
      in = w_out; out = woutT; R = 1024; N = 1024; tix = t & 31; tiy = t >> 5;
    }
    const int bx = tix * 32, by = tiy * 32;
    const int tx = threadIdx.x & 31, ty = threadIdx.x >> 5;
    #pragma unroll
    for (int j = 0; j < 32; j += 8)
      tile[ty + j][tx] = in[(size_t)(by + ty + j) * N + bx + tx];
    __syncthreads();
    const int s = threadIdx.x;
    if (s < 128) {
      int row = s >> 2, seg = (s & 3) * 8;
      short r[8];
      #pragma unroll
      for (int j = 0; j < 8; ++j) r[j] = f2bf(tile[seg + j][row]);
      *(int4*)&out[(size_t)(bx + row) * R + by + seg] = *(int4*)r;
    }
  }
}

// ---------------- GEMM QKV: 128x128 tile, BK=64; coalesced epilogues via LDS ----------------
__global__ __launch_bounds__(256) void gemm_qkv(const short* __restrict__ A,
                                                const short* __restrict__ Bt,
                                                const float* __restrict__ bias,
                                                short* __restrict__ Qo,
                                                short* __restrict__ Ko,
                                                short* __restrict__ Vt) {
  __shared__ short smem[128 * 132];
  short* sA = smem;
  short* sB = smem + 128 * 64;
  const int tid = threadIdx.x;
  const int w = tid >> 6, lane = tid & 63;
  const int wm = w >> 1, wn = w & 1;
  const int g = lane >> 4, r16 = lane & 15;
  const int m0 = blockIdx.x * 128, n0 = blockIdx.y * 128;
  const int krow = lane >> 3, kslot = lane & 7;

  f32x4 acc[4][4] = {};

  for (int k0 = 0; k0 < 1024; k0 += 64) {
    __syncthreads();
    #pragma unroll
    for (int p = 0; p < 4; ++p) {
      int rbase = w * 32 + p * 8;
      int row = rbase + krow;
      GLD16(&A[(size_t)(m0 + row) * 1024 + k0 + ((kslot ^ (row & 7)) * 8)], &sA[rbase * 64]);
      GLD16(&Bt[(size_t)(n0 + row) * 1024 + k0 + ((kslot ^ (row & 7)) * 8)], &sB[rbase * 64]);
    }
    __syncthreads();
    bf16x8 af[4][2], bf[4][2];
    #pragma unroll
    for (int mi = 0; mi < 4; ++mi) {
      int row = wm * 64 + mi * 16 + r16;
      #pragma unroll
      for (int c = 0; c < 2; ++c)
        af[mi][c] = *(const bf16x8*)&sA[row * 64 + (((c * 4 + g) ^ (row & 7)) * 8)];
    }
    #pragma unroll
    for (int ni = 0; ni < 4; ++ni) {
      int row = wn * 64 + ni * 16 + r16;
      #pragma unroll
      for (int c = 0; c < 2; ++c)
        bf[ni][c] = *(const bf16x8*)&sB[row * 64 + (((c * 4 + g) ^ (row & 7)) * 8)];
    }
    __builtin_amdgcn_s_setprio(1);
    #pragma unroll
    for (int mi = 0; mi < 4; ++mi)
      #pragma unroll
      for (int ni = 0; ni < 4; ++ni) {
        acc[mi][ni] = __builtin_amdgcn_mfma_f32_16x16x32_bf16(af[mi][0], bf[ni][0], acc[mi][ni], 0, 0, 0);
        acc[mi][ni] = __builtin_amdgcn_mfma_f32_16x16x32_bf16(af[mi][1], bf[ni][1], acc[mi][ni], 0, 0, 0);
      }
    __builtin_amdgcn_s_setprio(0);
  }

  const int b2 = m0 >> 11, t0l = m0 & 2047;
  __syncthreads();

  if (n0 < 2048) {
    const int which = n0 >> 10;
    short* dst = (which == 0) ? Qo : Ko;
    const float sc = (which == 0) ? 0.18033688f : 1.0f;  // 0.125 * log2(e) into Q
    #pragma unroll
    for (int mi = 0; mi < 4; ++mi) {
      #pragma unroll
      for (int ni = 0; ni < 4; ++ni) {
        int nn = wn * 64 + ni * 16 + r16;
        float bv = bias[n0 + nn];
        #pragma unroll
        for (int rr = 0; rr < 4; ++rr) {
          int tm = wm * 64 + mi * 16 + g * 4 + rr;
          smem[tm * 132 + nn] = f2bf((acc[mi][ni][rr] + bv) * sc);
        }
      }
    }
    __syncthreads();
    const int h0 = (n0 & 1023) >> 6;
    const int c = lane & 15;
    const int head = h0 + (c >> 3);
    #pragma unroll
    for (int it = 0; it < 8; ++it) {
      int row = w * 32 + it * 4 + (lane >> 4);
      int4 v = *(const int4*)&smem[row * 132 + c * 8];
      *(int4*)&dst[(size_t)((b2 * H_ + head) * T_ + t0l + row) * 64 + (c & 7) * 8] = v;
    }
  } else {
    #pragma unroll
    for (int mi = 0; mi < 4; ++mi) {
      #pragma unroll
      for (int ni = 0; ni < 4; ++ni) {
        int nn = wn * 64 + ni * 16 + r16;
        float bv = bias[n0 + nn];
        #pragma unroll
        for (int rr = 0; rr < 4; ++rr) {
          int tm = wm * 64 + mi * 16 + g * 4 + rr;
          int tp = (tm & ~0x1C) | ((tm & 0xC) << 1) | ((tm & 0x10) >> 2);  // within-64 slot perm
          smem[nn * 132 + tp] = f2bf(acc[mi][ni][rr] + bv);
        }
      }
    }
    __syncthreads();
    const int head0 = b2 * H_ + ((n0 - 2048) >> 6);
    const int c = lane & 15;
    #pragma unroll
    for (int it = 0; it < 8; ++it) {
      int row = w * 32 + it * 4 + (lane >> 4);
      int d = row & 63, hh2 = row >> 6;
      int4 v = *(const int4*)&smem[row * 132 + c * 8];
      *(int4*)&Vt[((size_t)(head0 + hh2) * D_ + d) * T_ + t0l + c * 8] = v;
    }
  }
}

// ---------------- GEMM out: 128x64 tile (512 blocks = 2/CU), BK=64 ----------------
__global__ __launch_bounds__(256) void gemm_out(const short* __restrict__ A,
                                                const short* __restrict__ Bt,
                                                const float* __restrict__ bias,
                                                float* __restrict__ Out) {
  __shared__ short sA[128 * 64];
  __shared__ short sB[64 * 64];
  const int tid = threadIdx.x;
  const int w = tid >> 6, lane = tid & 63;
  const int wm = w >> 1, wn = w & 1;
  const int g = lane >> 4, r16 = lane & 15;
  const int m0 = blockIdx.x * 128, n0 = blockIdx.y * 64;
  const int krow = lane >> 3, kslot = lane & 7;

  f32x4 acc[4][2] = {};

  for (int k0 = 0; k0 < 1024; k0 += 64) {
    __syncthreads();
    #pragma unroll
    for (int p = 0; p < 4; ++p) {
      int rbase = w * 32 + p * 8;
      int row = rbase + krow;
      GLD16(&A[(size_t)(m0 + row) * 1024 + k0 + ((kslot ^ (row & 7)) * 8)], &sA[rbase * 64]);
    }
    #pragma unroll
    for (int p = 0; p < 2; ++p) {
      int rbase = w * 16 + p * 8;
      int row = rbase + krow;
      GLD16(&Bt[(size_t)(n0 + row) * 1024 + k0 + ((kslot ^ (row & 7)) * 8)], &sB[rbase * 64]);
    }
    __syncthreads();
    bf16x8 af[4][2], bf[2][2];
    #pragma unroll
    for (int mi = 0; mi < 4; ++mi) {
      int row = wm * 64 + mi * 16 + r16;
      #pragma unroll
      for (int c = 0; c < 2; ++c)
        af[mi][c] = *(const bf16x8*)&sA[row * 64 + (((c * 4 + g) ^ (row & 7)) * 8)];
    }
    #pragma unroll
    for (int ni = 0; ni < 2; ++ni) {
      int row = wn * 32 + ni * 16 + r16;
      #pragma unroll
      for (int c = 0; c < 2; ++c)
        bf[ni][c] = *(const bf16x8*)&sB[row * 64 + (((c * 4 + g) ^ (row & 7)) * 8)];
    }
    __builtin_amdgcn_s_setprio(1);
    #pragma unroll
    for (int mi = 0; mi < 4; ++mi)
      #pragma unroll
      for (int ni = 0; ni < 2; ++ni) {
        acc[mi][ni] = __builtin_amdgcn_mfma_f32_16x16x32_bf16(af[mi][0], bf[ni][0], acc[mi][ni], 0, 0, 0);
        acc[mi][ni] = __builtin_amdgcn_mfma_f32_16x16x32_bf16(af[mi][1], bf[ni][1], acc[mi][ni], 0, 0, 0);
      }
    __builtin_amdgcn_s_setprio(0);
  }

  #pragma unroll
  for (int mi = 0; mi < 4; ++mi) {
    #pragma unroll
    for (int ni = 0; ni < 2; ++ni) {
      int n = n0 + wn * 32 + ni * 16 + r16;
      float bv = bias[n];
      #pragma unroll
      for (int rr = 0; rr < 4; ++rr) {
        int m = m0 + wm * 64 + mi * 16 + g * 4 + rr;
        Out[(size_t)m * 1024 + n] = acc[mi][ni][rr] + bv;
      }
    }
  }
}

// ---------------- flash attention: K-split + all-DMA staging (K and Vt both GLD16) --------
__global__ __launch_bounds__(256, 4) void attn_fwd(const short* __restrict__ Q,
                                                   const short* __restrict__ K,
                                                   const short* __restrict__ Vt,
                                                   short* __restrict__ O,
                                                   short* __restrict__ part,
                                                   float* __restrict__ ml) {
  __shared__ short sK[2][64 * 64];   // [key][d],  chunk c holds d-chunk c^(key&7)
  __shared__ short vT[2][64 * 64];   // [d][slot], chunk c holds slot-chunk c^(d&7)

  const int tid = threadIdx.x;
  const int w = tid >> 6, lane = tid & 63;
  const int g = lane >> 4, r16 = lane & 15;
  const int bh = blockIdx.x;
  const int b = bh >> 4, hh = bh & 15;
  const int yy = blockIdx.y;
  const int k3 = yy / 3, r3 = yy - 3 * k3;
  const int split = (r3 != 2);
  const int qi = split ? (31 - k3) : (15 - k3);
  const int half = split ? r3 : 0;
  const int q0 = qi * 64;
  const int kt0 = (split && half) ? ((qi + 1) >> 1) : 0;
  const int kt1 = (split && !half) ? ((qi + 1) >> 1) : (qi + 1);

  const short* Qh = Q + (size_t)bh * T_ * D_;
  const short* Kh = K + (size_t)bh * T_ * D_;
  const short* Vh = Vt + (size_t)bh * D_ * T_;   // [d][t'] slot-permuted

  const int krw = lane >> 3;
  const int kslot = lane & 7;

  const int qrow_a = q0 + w * 16 + r16;
  bf16x8 qf[2];
  qf[0] = *(const bf16x8*)&Qh[(size_t)qrow_a * 64 + g * 8];
  qf[1] = *(const bf16x8*)&Qh[(size_t)qrow_a * 64 + 32 + g * 8];

  f32x4 o[4] = {};
  float m_ = -1e30f, l_ = 0.f;   // per-lane partial l (scale 2^-m_)

  {
    const int k0 = kt0 * 64;
    #pragma unroll
    for (int p = 0; p < 2; ++p) {
      int row = w * 16 + p * 8 + krw;
      GLD16(&Kh[(size_t)(k0 + row) * 64 + ((kslot ^ (row & 7)) * 8)],
            &sK[0][(w * 16 + p * 8) * 64]);
      GLD16(&Vh[(size_t)row * T_ + k0 + ((kslot ^ (row & 7)) * 8)],
            &vT[0][(w * 16 + p * 8) * 64]);
    }
  }
  __syncthreads();

  for (int kt = kt0; kt < kt1; ++kt) {
    const int cur = (kt - kt0) & 1, nxt = cur ^ 1;
    const int k0 = kt * 64;
    const bool pf = (kt + 1 < kt1);

    if (pf) {
      const int k1 = k0 + 64;
      #pragma unroll
      for (int p = 0; p < 2; ++p) {
        int row = w * 16 + p * 8 + krw;
        GLD16(&Kh[(size_t)(k1 + row) * 64 + ((kslot ^ (row & 7)) * 8)],
              &sK[nxt][(w * 16 + p * 8) * 64]);
        GLD16(&Vh[(size_t)row * T_ + k1 + ((kslot ^ (row & 7)) * 8)],
              &vT[nxt][(w * 16 + p * 8) * 64]);
      }
    }

    // ---- S^T = K Q^T : lane holds S[key = nt*16+4g+rr][q = r16] ----
    f32x4 s[4] = {};
    __builtin_amdgcn_s_setprio(1);
    #pragma unroll
    for (int nt = 0; nt < 4; ++nt) {
      const int row = nt * 16 + r16;
      const int sw8 = r16 & 7;
      bf16x8 kf0 = *(const bf16x8*)&sK[cur][row * 64 + ((g ^ sw8) * 8)];
      bf16x8 kf1 = *(const bf16x8*)&sK[cur][row * 64 + (((4 + g) ^ sw8) * 8)];
      s[nt] = __builtin_amdgcn_mfma_f32_16x16x32_bf16(kf0, qf[0], s[nt], 0, 0, 0);
      s[nt] = __builtin_amdgcn_mfma_f32_16x16x32_bf16(kf1, qf[1], s[nt], 0, 0, 0);
    }
    __builtin_amdgcn_s_setprio(0);

    // ---- online softmax: zero cross-lane ops in the common path ----
    if (kt == qi) {
      const int qrow = w * 16 + r16;
      #pragma unroll
      for (int nt = 0; nt < 4; ++nt)
        #pragma unroll
        for (int rr = 0; rr < 4; ++rr)
          if (nt * 16 + 4 * g + rr > qrow) s[nt][rr] = -1e30f;
    }
    float pmax = s[0][0];
    #pragma unroll
    for (int nt = 0; nt < 4; ++nt)
      #pragma unroll
      for (int rr = 0; rr < 4; ++rr)
        pmax = fmaxf(pmax, s[nt][rr]);
    if (!__all(pmax - m_ <= 8.0f)) {  // defer-max (T13)
      float rmax = fmaxf(pmax, __shfl_xor(pmax, 16));
      rmax = fmaxf(rmax, __shfl_xor(rmax, 32));
      float mn = fmaxf(m_, rmax);
      float al = __builtin_amdgcn_exp2f(m_ - mn);
      m_ = mn;
      l_ *= al;
      float av[4];
      #pragma unroll
      for (int rr = 0; rr < 4; ++rr) av[rr] = __shfl(al, 4 * g + rr, 16);
      #pragma unroll
      for (int nt = 0; nt < 4; ++nt)
        #pragma unroll
        for (int rr = 0; rr < 4; ++rr) o[nt][rr] *= av[rr];
    }
    float rs = 0.f;
    #pragma unroll
    for (int nt = 0; nt < 4; ++nt)
      #pragma unroll
      for (int rr = 0; rr < 4; ++rr) {
        float p = __builtin_amdgcn_exp2f(s[nt][rr] - m_);
        s[nt][rr] = p;
        rs += p;
      }
    l_ += rs;
    int pk[8];
    #pragma unroll
    for (int nt = 0; nt < 4; ++nt)
      #pragma unroll
      for (int h = 0; h < 2; ++h)
        asm("v_cvt_pk_bf16_f32 %0, %1, %2"
            : "=v"(pk[nt * 2 + h])
            : "v"(s[nt][2 * h]), "v"(s[nt][2 * h + 1]));

    // ---- O += P @ V : packed P is the A-fragment directly ----
    bf16x8 pa[2];
    {
      int4 t0; t0.x = pk[0]; t0.y = pk[1]; t0.z = pk[2]; t0.w = pk[3];
      int4 t1; t1.x = pk[4]; t1.y = pk[5]; t1.z = pk[6]; t1.w = pk[7];
      pa[0] = __builtin_bit_cast(bf16x8, t0);
      pa[1] = __builtin_bit_cast(bf16x8, t1);
    }
    __builtin_amdgcn_s_setprio(1);
    #pragma unroll
    for (int nt = 0; nt < 4; ++nt) {
      const int d = nt * 16 + r16;
      bf16x8 vb0 = *(const bf16x8*)&vT[cur][d * 64 + ((g ^ (d & 7)) * 8)];
      bf16x8 vb1 = *(const bf16x8*)&vT[cur][d * 64 + (((4 + g) ^ (d & 7)) * 8)];
      o[nt] = __builtin_amdgcn_mfma_f32_16x16x32_bf16(pa[0], vb0, o[nt], 0, 0, 0);
      o[nt] = __builtin_amdgcn_mfma_f32_16x16x32_bf16(pa[1], vb1, o[nt], 0, 0, 0);
    }
    __builtin_amdgcn_s_setprio(0);

    __syncthreads();
  }

  // ---- epilogue: reduce per-lane l partials once ----
  float lt = l_ + __shfl_xor(l_, 16);
  lt += __shfl_xor(lt, 32);
  float lv[4];
  #pragma unroll
  for (int rr = 0; rr < 4; ++rr) lv[rr] = __shfl(lt, 4 * g + rr, 16);

  if (!split || half == 0) {
    #pragma unroll
    for (int nt = 0; nt < 4; ++nt) {
      int d = nt * 16 + r16;
      #pragma unroll
      for (int rr = 0; rr < 4; ++rr) {
        int t = q0 + w * 16 + 4 * g + rr;
        O[(size_t)(b * T_ + t) * C_ + hh * 64 + d] = f2bf(o[nt][rr] / lv[rr]);
      }
    }
  } else {
    const int p = qi - 16;
    #pragma unroll
    for (int nt = 0; nt < 4; ++nt) {
      int d = nt * 16 + r16;
      #pragma unroll
      for (int rr = 0; rr < 4; ++rr) {
        int row = w * 16 + 4 * g + rr;
        part[((size_t)((bh * 16 + p) * 64 + row)) * 64 + d] = f2bf(o[nt][rr] / lv[rr]);
      }
    }
  }
  if (split && lane < 16) {
    const int p = qi - 16;
    int mi = (bh * 16 + p) * 64 + w * 16 + lane;
    ml[half * MLS + mi] = m_;
    ml[(2 + half) * MLS + mi] = lt;
  }
}

// ---------------- combine: merge split-tile partials ----------------
__global__ __launch_bounds__(256) void attn_combine(const short* __restrict__ part,
                                                    const float* __restrict__ ml,
                                                    short* __restrict__ O) {
  const int bh = blockIdx.x, p = blockIdx.y;
  const int qi = 16 + p;
  const int b = bh >> 4, hh = bh & 15;
  const int tid = threadIdx.x;
  const int row = tid >> 2;
  const int d0 = (tid & 3) * 16;
  const int mi = (bh * 16 + p) * 64 + row;
  float m1 = ml[mi],           m2 = ml[MLS + mi];
  float l1 = ml[2 * MLS + mi], l2 = ml[3 * MLS + mi];
  float ms = fmaxf(m1, m2);
  float w1 = l1 * __builtin_amdgcn_exp2f(m1 - ms);
  float w2 = l2 * __builtin_amdgcn_exp2f(m2 - ms);
  float inv = 1.0f / (w1 + w2);
  w1 *= inv; w2 *= inv;
  short* op = O + ((size_t)(b * T_ + qi * 64 + row) * C_) + hh * 64 + d0;
  const short* pp = part + ((size_t)((bh * 16 + p) * 64 + row)) * 64 + d0;
  #pragma unroll
  for (int v = 0; v < 2; ++v) {
    int4 a = *(const int4*)(op + v * 8);
    int4 c = *(const int4*)(pp + v * 8);
    const short* as = (const short*)&a;
    const short* cs = (const short*)&c;
    short r[8];
    #pragma unroll
    for (int j = 0; j < 8; ++j) {
      float o1 = __builtin_bit_cast(float, ((unsigned)(unsigned short)as[j]) << 16);
      float o2 = __builtin_bit_cast(float, ((unsigned)(unsigned short)cs[j]) << 16);
      r[j] = f2bf(w1 * o1 + w2 * o2);
    }
    *(int4*)(op + v * 8) = *(int4*)r;
  }
}

extern "C" void kernel_launch(void* const* d_in, const int* in_sizes, int n_in,
                              void* d_out, int out_size, void* d_ws, size_t ws_size,
                              hipStream_t stream) {
  const float* x     = (const float*)d_in[0];
  const float* w_qkv = (const float*)d_in[1];
  const float* b_qkv = (const float*)d_in[2];
  const float* w_out = (const float*)d_in[3];
  const float* b_out = (const float*)d_in[4];
  float* out = (float*)d_out;

  char* ws = (char*)d_ws;
  if (ws_size < (size_t)(40u << 20)) return;

  short* xb     = (short*)(ws);                        // 8 MiB  [4096][1024] bf16
  short* wqkvT  = (short*)(ws + ((size_t)8u << 20));   // 6 MiB  (dead after gemm_qkv)
  short* woutT  = (short*)(ws + ((size_t)14u << 20));  // 2 MiB
  short* Qb     = (short*)(ws + ((size_t)16u << 20));  // 8 MiB  [B][H][T][D] (prescaled)
  short* Kb     = (short*)(ws + ((size_t)24u << 20));  // 8 MiB  [B][H][T][D]
  short* Vtb    = (short*)(ws + ((size_t)32u << 20));  // 8 MiB  [B][H][D][T'] slot-permuted
  short* attn_o = xb;                                  // xb dead after gemm_qkv
  short* part   = wqkvT;                               // 4 MiB partial O (half1)
  float* ml     = (float*)(ws + ((size_t)12u << 20));  // 0.5 MiB m/l partials

  prep<<<6144, 256, 0, stream>>>(x, w_qkv, w_out, xb, wqkvT, woutT);
  gemm_qkv<<<dim3(32, 24), 256, 0, stream>>>(xb, wqkvT, b_qkv, Qb, Kb, Vtb);
  attn_fwd<<<dim3(32, 48), 256, 0, stream>>>(Qb, Kb, Vtb, attn_o, part, ml);
  attn_combine<<<dim3(32, 16), 256, 0, stream>>>(part, ml, attn_o);
  gemm_out<<<dim3(32, 16), 256, 0, stream>>>(attn_o, woutT, b_out, out);
}